// Round 4
// baseline (114.033 us; speedup 1.0000x reference)
//
#include <hip/hip_runtime.h>
#include <hip/hip_fp16.h>

// FlowAlignedSmoothingEffect — round 8: re-unified 16B LDS records.
//
// R7 post-mortem: 2px/thread ILP regressed (108.4 -> 111.0us) — reverted.
// Conflict-history audit: R4 (16B uint4, b128) cost ~14 cyc/read; R5/R6
// (split 8B, b64) cost ~13.5 cyc/read but TWICE the reads. Per-instr conflict
// overhead comes from divergent march-position jitter (+-3px per lane), which
// hits both layouts equally — so the R5 split doubled LDS-pipe time. Undo it:
//  * one uint4 record {tanx f32, tany f32, (c0,c1) f16x2, (c2,_) f16x2};
//    ONE ds_read_b128 per bilinear corner gives tangent AND color ->
//    24 b128/wave vs 40 b64 (-40% LDS pipe cycles, half the issue slots,
//    half the latency events on the serial tangent chain).
//  * everything else = proven R6: 16x16 tile, 25x25 window (row stride 100
//    words == 4 mod 32 keeps bank rotation), packed-f16 color bilinear with
//    f32 accumulation, EXACT f32 tangent march (bit-identical), last-live-iter
//    tangent skip, interior/border specialization, XCD-chunked swizzle.

#define HH 1024
#define WW 1024
#define CC 3
#define BB 2
#define NPIX (HH * WW)

#define TSX 16
#define TSY 16
#define HALO_LO 4
#define NWIN 25            // 4 + 16 + 5

__device__ __forceinline__ __half2 h2(unsigned u) {
    __half2 r; *(unsigned*)&r = u; return r;
}

__global__ __launch_bounds__(256) void flow_smooth_lds(
    const float* __restrict__ x, const float* __restrict__ tng,
    const float* __restrict__ sigma, float* __restrict__ out)
{
    __shared__ uint4 win[NWIN * NWIN];   // 10000 B

    // ---- XCD-chunked bijective block swizzle (8 XCDs, 8192 wgs) ----
    const int id  = (int)blockIdx.x + ((int)blockIdx.y << 6) + ((int)blockIdx.z << 12);
    const int swz = ((id & 7) << 10) + (id >> 3);
    const int bx = swz & 63;
    const int by = (swz >> 6) & 63;
    const int b  = swz >> 12;

    const int tile_x0 = bx * TSX;
    const int tile_y0 = by * TSY;
    const int win_x0 = tile_x0 - HALO_LO;
    const int win_y0 = tile_y0 - HALO_LO;
    const bool border = (bx == 0) | (bx == 63) | (by == 0) | (by == 63);

    const float* __restrict__ xb  = x   + (size_t)b * CC * NPIX;
    const float* __restrict__ tbx = tng + (size_t)b * 2 * NPIX;
    const float* __restrict__ tby = tbx + NPIX;

    // ---- stage 25x25 window into LDS ----
    if (!border) {
        const int gbase = win_y0 * WW + win_x0;
        for (unsigned j = threadIdx.x; j < NWIN * NWIN; j += 256) {
            const int jy = (int)(j / NWIN);
            const int jx = (int)j - jy * NWIN;
            const int g = gbase + (jy << 10) + jx;
            const __half2 c01 = __floats2half2_rn(xb[g], xb[NPIX + g]);
            const __half2 c2p = __floats2half2_rn(xb[2 * NPIX + g], 0.f);
            uint4 r;
            r.x = __float_as_uint(tbx[g]);
            r.y = __float_as_uint(tby[g]);
            r.z = *(const unsigned*)&c01;
            r.w = *(const unsigned*)&c2p;
            win[j] = r;
        }
    } else {
        for (unsigned j = threadIdx.x; j < NWIN * NWIN; j += 256) {
            const int jy = (int)(j / NWIN);
            const int jx = (int)j - jy * NWIN;
            const int gy = min(max(win_y0 + jy, 0), HH - 1);
            const int gx = min(max(win_x0 + jx, 0), WW - 1);
            const int g = gy * WW + gx;
            const __half2 c01 = __floats2half2_rn(xb[g], xb[NPIX + g]);
            const __half2 c2p = __floats2half2_rn(xb[2 * NPIX + g], 0.f);
            uint4 r;
            r.x = __float_as_uint(tbx[g]);
            r.y = __float_as_uint(tby[g]);
            r.z = *(const unsigned*)&c01;
            r.w = *(const unsigned*)&c2p;
            win[j] = r;
        }
    }
    __syncthreads();

    // ---- per-pixel setup ----
    const int tx = threadIdx.x & (TSX - 1);
    const int ty = threadIdx.x >> 4;
    const int ix = tile_x0 + tx;
    const int iy = tile_y0 + ty;
    const int pix = iy * WW + ix;

    const float sig = sigma[b];
    const float half_width = 2.0f * sig;
    const float inv2s2 = 1.0f / (2.0f * sig * sig);
    const float step = (float)(1.0 / 0.3333);

    // per-batch-uniform Gaussian weights + live trip count (sigma < 6 => <= 3)
    const float r0 = step;
    const float r1 = r0 + step;
    const float r2 = r1 + step;
    const int nlive = (int)(r0 < half_width) + (int)(r1 < half_width) + (int)(r2 < half_width);
    const float kk0 = __expf(-r0 * r0 * inv2s2);
    const float kk1 = __expf(-r1 * r1 * inv2s2);
    const float kk2 = __expf(-r2 * r2 * inv2s2);

    // exact f32 center color (global, coalesced, L2-warm) + exact tangent (LDS)
    const float xc0 = xb[pix];
    const float xc1 = xb[NPIX + pix];
    const float xc2 = xb[2 * NPIX + pix];
    const int cidx = (ty + HALO_LO) * NWIN + (tx + HALO_LO);
    const uint4 qc = win[cidx];
    const float t0x = __uint_as_float(qc.x);
    const float t0y = __uint_as_float(qc.y);

    const float invW = 1.0f / WW;
    const float invH = 1.0f / HH;

    float acc0 = 0.f, acc1 = 0.f, acc2 = 0.f, accs = 0.f;

    float vx[2], vy[2], px[2], py[2];
    vx[0] = t0x;  vy[0] = t0y;
    vx[1] = -t0x; vy[1] = -t0y;
    const float p0x = ((float)ix + 0.5f) * invW;
    const float p0y = ((float)iy + 0.5f) * invH;
    px[0] = p0x + vx[0] * invW;  py[0] = p0y + vy[0] * invH;
    px[1] = p0x + vx[1] * invW;  py[1] = p0y + vy[1] * invH;

    if (!border) {
        // ===== interior fast path =====
        const int winoff = win_y0 * NWIN + win_x0;
        #pragma unroll
        for (int it = 0; it < 3; ++it) {
            if (it >= nlive) break;
            const float k = (it == 0) ? kk0 : (it == 1) ? kk1 : kk2;
            const bool need_t = (it + 1 < nlive);   // last live iter: march is dead
            #pragma unroll
            for (int c = 0; c < 2; ++c) {
                const float fx = fmaf(px[c], (float)WW, -0.5f);
                const float fy = fmaf(py[c], (float)HH, -0.5f);
                const float x0f = floorf(fx);
                const float y0f = floorf(fy);
                const float wx = fx - x0f;
                const float wy = fy - y0f;
                const int idx = (int)y0f * NWIN + (int)x0f - winoff;

                const float wxm = 1.f - wx, wym = 1.f - wy;
                const float w00 = wxm * wym, w01 = wx * wym;
                const float w10 = wxm * wy,  w11 = wx * wy;

                // one b128 per corner: tangent f32 + color f16x2
                const uint4 q00 = win[idx];
                const uint4 q01 = win[idx + 1];
                const uint4 q10 = win[idx + NWIN];
                const uint4 q11 = win[idx + NWIN + 1];

                // packed-f16 color bilinear (accumulate in f32)
                const __half2 h00 = __float2half2_rn(w00);
                const __half2 h01 = __float2half2_rn(w01);
                const __half2 h10 = __float2half2_rn(w10);
                const __half2 h11 = __float2half2_rn(w11);
                __half2 a01 = __hmul2(h00, h2(q00.z));
                a01 = __hfma2(h01, h2(q01.z), a01);
                a01 = __hfma2(h10, h2(q10.z), a01);
                a01 = __hfma2(h11, h2(q11.z), a01);
                __half2 a2 = __hmul2(h00, h2(q00.w));
                a2 = __hfma2(h01, h2(q01.w), a2);
                a2 = __hfma2(h10, h2(q10.w), a2);
                a2 = __hfma2(h11, h2(q11.w), a2);
                acc0 = fmaf(k, __low2float(a01), acc0);
                acc1 = fmaf(k, __high2float(a01), acc1);
                acc2 = fmaf(k, __low2float(a2), acc2);

                if (need_t) {
                    // exact-f32 tangent interp + coherence flip (R6-identical)
                    float tfx = __uint_as_float(q00.x) * w00 + __uint_as_float(q01.x) * w01
                              + __uint_as_float(q10.x) * w10 + __uint_as_float(q11.x) * w11;
                    float tfy = __uint_as_float(q00.y) * w00 + __uint_as_float(q01.y) * w01
                              + __uint_as_float(q10.y) * w10 + __uint_as_float(q11.y) * w11;
                    const float vt = vx[c] * tfx + vy[c] * tfy;
                    const unsigned sgn = __float_as_uint(vt) & 0x80000000u;
                    tfx = __uint_as_float(__float_as_uint(tfx) ^ sgn);
                    tfy = __uint_as_float(__float_as_uint(tfy) ^ sgn);
                    vx[c] = tfx; vy[c] = tfy;
                    px[c] += tfx * invW;
                    py[c] += tfy * invH;
                }
            }
        }
        // accs is block-uniform in the interior (inb always true)
        float ks = 0.f;
        if (nlive > 0) ks += kk0;
        if (nlive > 1) ks += kk1;
        if (nlive > 2) ks += kk2;
        accs = 2.0f * ks;
    } else {
        // ===== border path: exact reference clamp semantics =====
        #pragma unroll
        for (int it = 0; it < 3; ++it) {
            if (it >= nlive) break;
            const float k = (it == 0) ? kk0 : (it == 1) ? kk1 : kk2;
            #pragma unroll
            for (int c = 0; c < 2; ++c) {
                const float fx = fmaf(px[c], (float)WW, -0.5f);
                const float fy = fmaf(py[c], (float)HH, -0.5f);
                const float x0f = floorf(fx);
                const float y0f = floorf(fy);
                const float wx = fx - x0f;      // weights from UNclamped floor
                const float wy = fy - y0f;
                int x0i = (int)x0f;
                int y0i = (int)y0f;
                x0i = min(max(x0i, 0), WW - 1); // clamp BEFORE +1 (ref order)
                y0i = min(max(y0i, 0), HH - 1);
                const int x1i = min(x0i + 1, WW - 1);
                const int y1i = min(y0i + 1, HH - 1);

                const int jx0 = x0i - win_x0;
                const int jx1 = x1i - win_x0;
                const int jy0 = y0i - win_y0;
                const int jy1 = y1i - win_y0;

                const uint4 q00 = win[jy0 * NWIN + jx0];
                const uint4 q01 = win[jy0 * NWIN + jx1];
                const uint4 q10 = win[jy1 * NWIN + jx0];
                const uint4 q11 = win[jy1 * NWIN + jx1];

                const float wxm = 1.f - wx, wym = 1.f - wy;
                const float w00 = wxm * wym, w01 = wx * wym;
                const float w10 = wxm * wy,  w11 = wx * wy;

                const bool inb = (px[c] >= 0.f) & (px[c] < 1.f) &
                                 (py[c] >= 0.f) & (py[c] < 1.f);
                const float kg = inb ? k : 0.f;

                const __half2 h00 = __float2half2_rn(w00);
                const __half2 h01 = __float2half2_rn(w01);
                const __half2 h10 = __float2half2_rn(w10);
                const __half2 h11 = __float2half2_rn(w11);
                __half2 a01 = __hmul2(h00, h2(q00.z));
                a01 = __hfma2(h01, h2(q01.z), a01);
                a01 = __hfma2(h10, h2(q10.z), a01);
                a01 = __hfma2(h11, h2(q11.z), a01);
                __half2 a2 = __hmul2(h00, h2(q00.w));
                a2 = __hfma2(h01, h2(q01.w), a2);
                a2 = __hfma2(h10, h2(q10.w), a2);
                a2 = __hfma2(h11, h2(q11.w), a2);
                acc0 = fmaf(kg, __low2float(a01), acc0);
                acc1 = fmaf(kg, __high2float(a01), acc1);
                acc2 = fmaf(kg, __low2float(a2), acc2);
                accs += kg;

                float tfx = __uint_as_float(q00.x) * w00 + __uint_as_float(q01.x) * w01
                          + __uint_as_float(q10.x) * w10 + __uint_as_float(q11.x) * w11;
                float tfy = __uint_as_float(q00.y) * w00 + __uint_as_float(q01.y) * w01
                          + __uint_as_float(q10.y) * w10 + __uint_as_float(q11.y) * w11;
                const float vt = vx[c] * tfx + vy[c] * tfy;
                const unsigned sgn = __float_as_uint(vt) & 0x80000000u;
                tfx = __uint_as_float(__float_as_uint(tfx) ^ sgn);
                tfy = __uint_as_float(__float_as_uint(tfy) ^ sgn);
                vx[c] = tfx; vy[c] = tfy;
                px[c] += tfx * invW;
                py[c] += tfy * invH;
            }
        }
    }

    const float inv_den = 1.0f / (1.0f + accs);
    float* ob = out + (size_t)b * CC * NPIX;
    ob[pix]            = (xc0 + acc0) * inv_den;
    ob[NPIX + pix]     = (xc1 + acc1) * inv_den;
    ob[2 * NPIX + pix] = (xc2 + acc2) * inv_den;
}

extern "C" void kernel_launch(void* const* d_in, const int* in_sizes, int n_in,
                              void* d_out, int out_size, void* d_ws, size_t ws_size,
                              hipStream_t stream) {
    const float* x  = (const float*)d_in[0];
    const float* t  = (const float*)d_in[1];
    const float* sg = (const float*)d_in[2];
    float* out = (float*)d_out;

    dim3 grid(WW / TSX, HH / TSY, BB);
    flow_smooth_lds<<<grid, dim3(256), 0, stream>>>(x, t, sg, out);
}